// Round 8
// baseline (146.733 us; speedup 1.0000x reference)
//
#include <hip/hip_runtime.h>

// Problem constants (match reference): B=8192, P=32, D=128, V=100000
#define BB 8192
#define PP 32
#define DD 128
#define VV 100000

// Bucketing: group gathers by embed-table address so DRAM sees ordered,
// page-local traffic instead of 131K random 512B rows (R4/R6/R7 all
// plateaued at ~20-23us = 34MB at ~1.5TB/s random-access HBM rate).
#define BSHIFT 7                       // bucket = idx >> 7 (64KB windows)
#define NB     ((VV + 127) >> BSHIFT)  // 782 buckets
#define CAP    320                     // ~2x mean occupancy (168): safe
#define NSPLIT 2                       // blocks per bucket

// ws layout
#define CNT_OFF   0                          // int[1024]
#define TUP_OFF   4096                       // uint[NB*CAP] (stride CAP)
#define PART_OFF  (4096 + 1024 * CAP * 4)    // float[NB*NSPLIT]

__global__ void hs_init_kernel(int* __restrict__ cnt) {
    cnt[threadIdx.x] = 0;                    // 1024 threads, NB=782 used
}

// Scatter all valid (b,p) pairs into address-window buckets.
// Pack: idx(17) | b(13) | code(1) = 31 bits -> one uint32.
__global__ __launch_bounds__(256) void hs_scatter_kernel(
    const int* __restrict__ path,        // [B, P]
    const int* __restrict__ path_len,    // [B]
    const int* __restrict__ code,        // [B, P]
    int*       __restrict__ cnt,
    unsigned*  __restrict__ tuples)
{
    const int t = blockIdx.x * 256 + threadIdx.x;   // 0..65535
    #pragma unroll
    for (int k = 0; k < 4; ++k) {
        const int fl = t + k * 65536;    // flat pair id, coalesced reads
        const int b  = fl >> 5;
        const int p  = fl & 31;
        if (p < path_len[b]) {           // path_len: 32KB, L1/L2-cached
            const int idx = path[fl];
            const int cd  = code[fl];
            const int bkt = idx >> BSHIFT;
            const int pos = atomicAdd(&cnt[bkt], 1);
            if (pos < CAP)               // never hit with uniform data
                tuples[bkt * CAP + pos] =
                    ((unsigned)idx << 14) | ((unsigned)b << 1) | (unsigned)cd;
        }
    }
}

// Process buckets: NSPLIT blocks per bucket, quarter-wave per tuple.
// Embed reads within a block stay inside one 64KB table window ->
// DRAM-page/L2 locality; hidden rows (4MB total) are L2/L3-resident.
__global__ __launch_bounds__(256) void hs_bucket_kernel(
    const float*    __restrict__ hidden,   // [B, D]
    const float*    __restrict__ embed,    // [V, D]
    const unsigned* __restrict__ tuples,
    const int*      __restrict__ cnt,
    float*          __restrict__ partials) // [NB*NSPLIT]
{
    const int g   = blockIdx.x >> 1;       // bucket
    const int h   = blockIdx.x & 1;        // half
    const int tid = threadIdx.x;
    const int l   = tid & 63;
    const int w   = tid >> 6;
    const int q   = l >> 4;                // quarter in wave
    const int ql  = l & 15;                // lane in quarter

    int n = cnt[g];
    n = min(n, CAP);
    const int half  = (n + 1) >> 1;
    const int start = h * half;
    const int nn    = min(n, start + half) - start;   // tuples for this block

    __shared__ unsigned tl[(CAP + 1) / 2];            // 160 entries, 640B
    for (int i = tid; i < nn; i += 256)
        tl[i] = tuples[g * CAP + start + i];
    __syncthreads();

    const int slot = w * 4 + q;            // 0..15 quarter-slots per block
    float acc = 0.0f;                      // nonzero only on ql==0 lanes
    for (int base = 0; base < nn; base += 16) {
        const int id = base + slot;
        if (id < nn) {                     // quarter-uniform branch
            const unsigned u = tl[id];     // LDS broadcast within quarter
            const int idx = (int)(u >> 14);
            const int b   = (int)((u >> 1) & 8191);
            const int cd  = (int)(u & 1);
            const float4* erow = (const float4*)(embed  + (size_t)idx * DD);
            const float4* hrow = (const float4*)(hidden + (size_t)b   * DD);
            const float4 e0 = erow[ql],      e1 = erow[16 + ql];
            const float4 h0 = hrow[ql],      h1 = hrow[16 + ql];
            float d = e0.x * h0.x + e0.y * h0.y + e0.z * h0.z + e0.w * h0.w
                    + e1.x * h1.x + e1.y * h1.y + e1.z * h1.z + e1.w * h1.w;
            // reduce the 16 quarter partials (masks <16 stay in-quarter)
            d += __shfl_xor(d, 1);
            d += __shfl_xor(d, 2);
            d += __shfl_xor(d, 4);
            d += __shfl_xor(d, 8);
            if (ql == 0) {
                // loss = softplus(code ? -dot : dot), stable BCE form
                const float z = cd ? -d : d;
                acc += fmaxf(z, 0.0f) + __logf(1.0f + __expf(-fabsf(z)));
            }
        }
    }

    // wave reduce (non-contributing lanes hold 0), then block combine
    #pragma unroll
    for (int m = 1; m <= 32; m <<= 1) acc += __shfl_xor(acc, m);
    __shared__ float sl[4];
    if (l == 0) sl[w] = acc;
    __syncthreads();
    if (tid == 0) partials[blockIdx.x] = sl[0] + sl[1] + sl[2] + sl[3];
}

// Sum the 1564 block partials + sum(path_len), divide.
__global__ __launch_bounds__(1024) void hs_finalize_kernel(
    const float* __restrict__ partials,
    const int*   __restrict__ path_len,
    float*       __restrict__ out)
{
    const int tid = threadIdx.x;
    float ls = 0.0f, cs = 0.0f;
    for (int i = tid; i < NB * NSPLIT; i += 1024) ls += partials[i];
    #pragma unroll
    for (int k = 0; k < BB / 1024; ++k) cs += (float)path_len[tid + k * 1024];
    #pragma unroll
    for (int m = 1; m <= 32; m <<= 1) {
        ls += __shfl_xor(ls, m);
        cs += __shfl_xor(cs, m);
    }
    __shared__ float s_l[16], s_c[16];
    const int wave = tid >> 6;
    if ((tid & 63) == 0) { s_l[wave] = ls; s_c[wave] = cs; }
    __syncthreads();
    if (tid == 0) {
        float L = 0.0f, C = 0.0f;
        #pragma unroll
        for (int wv = 0; wv < 16; ++wv) { L += s_l[wv]; C += s_c[wv]; }
        out[0] = L / C;
    }
}

extern "C" void kernel_launch(void* const* d_in, const int* in_sizes, int n_in,
                              void* d_out, int out_size, void* d_ws, size_t ws_size,
                              hipStream_t stream) {
    const float* hidden   = (const float*)d_in[0];  // [B, D] f32
    // d_in[1] = target (unused by the reference computation)
    const int*   path     = (const int*)d_in[2];    // [B, P]
    const int*   path_len = (const int*)d_in[3];    // [B]
    const int*   code     = (const int*)d_in[4];    // [B, P]
    const float* embed    = (const float*)d_in[5];  // [V, D] f32
    float* out = (float*)d_out;

    char* ws = (char*)d_ws;
    int*      cnt      = (int*)(ws + CNT_OFF);
    unsigned* tuples   = (unsigned*)(ws + TUP_OFF);
    float*    partials = (float*)(ws + PART_OFF);

    hs_init_kernel<<<1, 1024, 0, stream>>>(cnt);
    hs_scatter_kernel<<<256, 256, 0, stream>>>(path, path_len, code,
                                               cnt, tuples);
    hs_bucket_kernel<<<NB * NSPLIT, 256, 0, stream>>>(hidden, embed,
                                                      tuples, cnt, partials);
    hs_finalize_kernel<<<1, 1024, 0, stream>>>(partials, path_len, out);
}

// Round 9
// 100.137 us; speedup vs baseline: 1.4653x; 1.4653x over previous
//
#include <hip/hip_runtime.h>

// Problem constants (match reference): B=8192, P=32, D=128, V=100000
#define BB 8192
#define PP 32
#define DD 128

// Minimal-line-lookup gather. One wave per batch row; block = 4 waves;
// grid = 2048 (8 blocks/CU). Each pair's 512B embed row is loaded by a
// full 32-lane HALF-WAVE as one float4/lane instruction -> 8 distinct
// 64B lines per pair, the theoretical minimum (R7's quarter-wave scheme
// touched 32 lines per wave instruction -> 4.2M total line-lookups; this
// is ~1.1M). Halves process interleaved pairs pid = 2j+h so the exec
// masks stay near-full for any len.
//
// MLP: 4 pair-loads batched into registers before any consumption
// (e[4] = 16 VGPRs keeps total <=64 -> 8 waves/SIMD, 32 waves/CU).
//
// Reduction: lane writes its 4-elem partial to a wave-private stride-33
// LDS slice (writes: banks distinct per half, 2-way across halves = free;
// reads: bank bijection, 2-way = free). Lane l then sums half the 32
// partials of pair (l&31) and combines with shfl_xor(32). No
// __syncthreads anywhere, no per-pair shuffle chains.
__global__ __launch_bounds__(256) void hs_loss_kernel(
    const float* __restrict__ hidden,      // [B, D]
    const int*   __restrict__ path,        // [B, P]
    const int*   __restrict__ path_len,    // [B]
    const int*   __restrict__ code,        // [B, P]
    const float* __restrict__ embed,       // [V, D]
    float2* __restrict__ partials)         // [BB] {loss_sum, len} per row
{
    const int tid = threadIdx.x;
    const int w   = tid >> 6;              // wave in block, 0..3
    const int l   = tid & 63;              // lane
    const int h   = l >> 5;                // half, 0 or 1
    const int hl  = l & 31;                // lane within half
    const int b   = blockIdx.x * 4 + w;    // this wave's batch row

    __shared__ float plds[4][PP * 33];     // 4 wave-private slices, 16.5 KB
    float* const myp = plds[w];

    const int len   = path_len[b];         // wave-uniform
    const int idx_l = path[b * PP + hl];   // lane hl holds pair hl's index
    const int cd_l  = code[b * PP + hl];   // (both halves duplicate)

    // lane's 16B slice of the hidden row (both halves identical -> L1 hit)
    const float4 hv = ((const float4*)(hidden + (size_t)b * DD))[hl];

    // ---- phase 1: batched full-row loads + partial dots ----
    #pragma unroll
    for (int batch = 0; batch < 4; ++batch) {
        const int p0 = batch * 8;          // this batch covers pids p0..p0+7
        if (p0 < len) {                    // wave-uniform batch skip
            int pid[4];
            float4 e[4];
            #pragma unroll
            for (int j = 0; j < 4; ++j) {
                pid[j] = p0 + 2 * j + h;   // halves interleave pairs
                const int idx = __shfl(idx_l, pid[j]);
                if (pid[j] < len)          // half-uniform exec mask
                    e[j] = ((const float4*)(embed + (size_t)idx * DD))[hl];
            }
            #pragma unroll
            for (int j = 0; j < 4; ++j) {
                if (pid[j] < len) {
                    const float pr = e[j].x * hv.x + e[j].y * hv.y
                                   + e[j].z * hv.z + e[j].w * hv.w;
                    myp[pid[j] * 33 + hl] = pr;
                }
            }
        }
    }

    // ---- phase 2: half-split partial-sum (same-wave LDS, no barrier) ----
    const int lp = l & 31;                 // pair this lane reduces
    const int kb = h * 16;                 // lanes 0-31: k 0..15; 32-63: 16..31
    float psum = 0.0f;
    #pragma unroll
    for (int k = 0; k < 16; ++k) psum += myp[lp * 33 + kb + k];
    const float dot = psum + __shfl_xor(psum, 32);

    // ---- phase 3: softplus + wave reduction ----
    float loss = 0.0f;
    if (l < 32 && lp < len) {
        // loss = softplus(code ? -dot : dot), stable BCE form
        const float z = cd_l ? -dot : dot;
        loss = fmaxf(z, 0.0f) + __logf(1.0f + __expf(-fabsf(z)));
    }
    #pragma unroll
    for (int m = 1; m <= 32; m <<= 1) loss += __shfl_xor(loss, m);
    if (l == 0) partials[b] = make_float2(loss, (float)len);
}

// Single-block reduction of the 8192 per-row partials + final divide.
__global__ __launch_bounds__(1024) void hs_finalize_kernel(
    const float2* __restrict__ partials, float* __restrict__ out)
{
    const int tid = threadIdx.x;
    float ls = 0.0f, cs = 0.0f;
    #pragma unroll
    for (int k = 0; k < BB / 1024; ++k) {
        const float2 v = partials[tid + k * 1024];
        ls += v.x;
        cs += v.y;
    }
    #pragma unroll
    for (int m = 1; m <= 32; m <<= 1) {
        ls += __shfl_xor(ls, m);
        cs += __shfl_xor(cs, m);
    }
    __shared__ float s_l[16], s_c[16];
    const int wave = tid >> 6;
    if ((tid & 63) == 0) { s_l[wave] = ls; s_c[wave] = cs; }
    __syncthreads();
    if (tid == 0) {
        float L = 0.0f, C = 0.0f;
        #pragma unroll
        for (int wv = 0; wv < 16; ++wv) { L += s_l[wv]; C += s_c[wv]; }
        out[0] = L / C;
    }
}

extern "C" void kernel_launch(void* const* d_in, const int* in_sizes, int n_in,
                              void* d_out, int out_size, void* d_ws, size_t ws_size,
                              hipStream_t stream) {
    const float* hidden   = (const float*)d_in[0];  // [B, D] f32
    // d_in[1] = target (unused by the reference computation)
    const int*   path     = (const int*)d_in[2];    // [B, P]
    const int*   path_len = (const int*)d_in[3];    // [B]
    const int*   code     = (const int*)d_in[4];    // [B, P]
    const float* embed    = (const float*)d_in[5];  // [V, D] f32
    float*  out      = (float*)d_out;
    float2* partials = (float2*)d_ws;               // 8192 * 8B = 64 KB

    hs_loss_kernel<<<BB / 4, 256, 0, stream>>>(hidden, path, path_len, code,
                                               embed, partials);
    hs_finalize_kernel<<<1, 1024, 0, stream>>>(partials, out);
}